// Round 1
// baseline (2728.318 us; speedup 1.0000x reference)
//
#include <hip/hip_runtime.h>
#include <math.h>

#define LSEQ 384
#define HD 256
#define PDIM 64
#define NHEAD 4
#define NBINS 65
#define BATCH 2

__device__ __forceinline__ float wsum(float v) {
#pragma unroll
    for (int o = 32; o > 0; o >>= 1) v += __shfl_xor(v, o);
    return v;
}
__device__ __forceinline__ float wmax(float v) {
#pragma unroll
    for (int o = 32; o > 0; o >>= 1) v = fmaxf(v, __shfl_xor(v, o));
    return v;
}
__device__ __forceinline__ float gelu_erf(float x) {
    return 0.5f * x * (1.0f + erff(x * 0.70710678f));
}
__device__ __forceinline__ float bcast(float v, int l) {
    return __int_as_float(__builtin_amdgcn_readlane(__float_as_int(v), l));
}

// h[b,l,:] = x[b,l,:] @ rp_w + rp_b + pos[l,:]
__global__ void k_h_init(const float* __restrict__ x, const float* __restrict__ rp_w,
                         const float* __restrict__ rp_b, const float* __restrict__ pos,
                         float* __restrict__ h) {
    __shared__ float xs[48];
    int row = blockIdx.x;            // b*L + l
    int l = row % LSEQ;
    int t = threadIdx.x;
    if (t < 48) xs[t] = x[row * 48 + t];
    __syncthreads();
    float acc = rp_b[t] + pos[l * HD + t];
#pragma unroll 8
    for (int a = 0; a < 48; ++a) acc += xs[a] * rp_w[a * HD + t];
    h[row * HD + t] = acc;
}

// pA[row,:] = h[row,:] @ wA (+ bA);  pB[row,:] = h[row,:] @ wB (+ bB); 128 threads
__global__ void k_proj2(const float* __restrict__ h, const float* __restrict__ wA,
                        const float* __restrict__ wB, const float* __restrict__ bA,
                        const float* __restrict__ bB,
                        float* __restrict__ pA, float* __restrict__ pB) {
    __shared__ float hs[HD];
    int row = blockIdx.x;
    int t = threadIdx.x;
    hs[t] = h[row * HD + t];
    hs[t + 128] = h[row * HD + t + 128];
    __syncthreads();
    int col = t & 63;
    const float* w = (t < 64) ? wA : wB;
    const float* bias = (t < 64) ? bA : bB;
    float acc = bias ? bias[col] : 0.0f;
#pragma unroll 8
    for (int a = 0; a < HD; ++a) acc += hs[a] * w[a * PDIM + col];
    float* p = (t < 64) ? pA : pB;
    p[row * PDIM + col] = acc;
}

// pair[b,i,j,:] = pi[b,i,:] + pj[b,j,:] + rel_emb[clip(j-i)+32,:]
__global__ void k_pair_init(const float* __restrict__ pi, const float* __restrict__ pj,
                            const float* __restrict__ rel_emb, float* __restrict__ pair) {
    __shared__ float pis[PDIM];
    int row = blockIdx.x;            // b*L + i
    int b = row / LSEQ, i = row % LSEQ;
    int t = threadIdx.x;
    if (t < PDIM) pis[t] = pi[row * PDIM + t];
    __syncthreads();
    const float* pjb = pj + (size_t)b * LSEQ * PDIM;
    float* pr = pair + (size_t)row * LSEQ * PDIM;
    for (int n = t; n < LSEQ * PDIM; n += 256) {
        int j = n >> 6, d = n & 63;
        int r = j - i; r = r < -32 ? -32 : (r > 32 ? 32 : r); r += 32;
        pr[n] = pis[d] + pjb[j * PDIM + d] + rel_emb[r * PDIM + d];
    }
}

// seq layernorm: one row per block
__global__ void k_ln_seq(const float* __restrict__ h, const float* __restrict__ g,
                         const float* __restrict__ b, float* __restrict__ out) {
    __shared__ float red[8];
    int row = blockIdx.x;
    int t = threadIdx.x;
    int w = t >> 6, lane = t & 63;
    float v = h[row * HD + t];
    float s = wsum(v);
    if (lane == 0) red[w] = s;
    __syncthreads();
    float mean = (red[0] + red[1] + red[2] + red[3]) * (1.0f / HD);
    float d = v - mean;
    float q = wsum(d * d);
    if (lane == 0) red[4 + w] = q;
    __syncthreads();
    float var = (red[4] + red[5] + red[6] + red[7]) * (1.0f / HD);
    out[row * HD + t] = d * rsqrtf(var + 1e-5f) * g[t] + b[t];
}

// mask[l,m] = (1/(B*NH)) * sum_b LN(pair[b,l,m,:]) . pbsum   — one wave per (l,m)
__global__ void k_mask(const float* __restrict__ pair, const float* __restrict__ g,
                       const float* __restrict__ bb, const float* __restrict__ pbw,
                       float* __restrict__ mask) {
    int wid = blockIdx.x * 4 + (threadIdx.x >> 6);
    int lane = threadIdx.x & 63;
    int l = wid / LSEQ, m = wid % LSEQ;
    float gd = g[lane], bd = bb[lane];
    float pbs = pbw[lane * 4] + pbw[lane * 4 + 1] + pbw[lane * 4 + 2] + pbw[lane * 4 + 3];
    float acc = 0.0f;
#pragma unroll
    for (int b = 0; b < BATCH; ++b) {
        float v = pair[(((size_t)(b * LSEQ + l)) * LSEQ + m) * PDIM + lane];
        float mean = wsum(v) * (1.0f / PDIM);
        float d = v - mean;
        float var = wsum(d * d) * (1.0f / PDIM);
        float ln = d * rsqrtf(var + 1e-5f) * gd + bd;
        acc += wsum(ln * pbs);
    }
    if (lane == 0) mask[l * LSEQ + m] = acc * (1.0f / (BATCH * NHEAD));
}

// qkv = seq_n @ in_w + in_b ; 8 rows per block
__global__ void k_qkv(const float* __restrict__ sn, const float* __restrict__ w,
                      const float* __restrict__ bias, float* __restrict__ qkv) {
    __shared__ float xs[8][HD];
    int r0 = blockIdx.x * 8;
    int t = threadIdx.x;
#pragma unroll
    for (int r = 0; r < 8; ++r) xs[r][t] = sn[(r0 + r) * HD + t];
    __syncthreads();
#pragma unroll
    for (int c = 0; c < 3; ++c) {
        int j = c * HD + t;
        float acc[8];
#pragma unroll
        for (int r = 0; r < 8; ++r) acc[r] = 0.0f;
        for (int a = 0; a < HD; ++a) {
            float wv = w[a * 768 + j];
#pragma unroll
            for (int r = 0; r < 8; ++r) acc[r] += xs[r][a] * wv;
        }
        float bv = bias[j];
#pragma unroll
        for (int r = 0; r < 8; ++r) qkv[(r0 + r) * 768 + j] = acc[r] + bv;
    }
}

// attention for one (b, nh, l) per block
__global__ void k_attn(const float* __restrict__ qkv, const float* __restrict__ mask,
                       float* __restrict__ o) {
    __shared__ __align__(16) float qs[64];
    __shared__ float sc[LSEQ];
    __shared__ float red[8];
    __shared__ float op[4][64];
    int bid = blockIdx.x;
    int l = bid % LSEQ;
    int nh = (bid / LSEQ) & 3;
    int b = bid / (LSEQ * NHEAD);
    int t = threadIdx.x;
    int w = t >> 6, lane = t & 63;
    const float* qbase = qkv + ((size_t)(b * LSEQ + l)) * 768 + nh * 64;
    if (t < 64) qs[t] = qbase[t];
    __syncthreads();
    float lmax = -1e30f;
    float myv[2];
#pragma unroll
    for (int it = 0; it < 2; ++it) {
        int m = t + it * 256;
        if (m < LSEQ) {
            const float* kb = qkv + ((size_t)(b * LSEQ + m)) * 768 + 256 + nh * 64;
            const float4* k4 = (const float4*)kb;
            const float4* q4 = (const float4*)qs;
            float acc = 0.0f;
#pragma unroll
            for (int a = 0; a < 16; ++a) {
                float4 kv = k4[a], qv = q4[a];
                acc += qv.x * kv.x + qv.y * kv.y + qv.z * kv.z + qv.w * kv.w;
            }
            float s = acc * 0.125f + mask[l * LSEQ + m];
            myv[it] = s;
            lmax = fmaxf(lmax, s);
        } else myv[it] = -1e30f;
    }
    float wm = wmax(lmax);
    if (lane == 0) red[w] = wm;
    __syncthreads();
    float gmax = fmaxf(fmaxf(red[0], red[1]), fmaxf(red[2], red[3]));
    float lsum = 0.0f;
#pragma unroll
    for (int it = 0; it < 2; ++it) {
        int m = t + it * 256;
        if (m < LSEQ) {
            float e = expf(myv[it] - gmax);
            sc[m] = e;
            lsum += e;
        }
    }
    float ws = wsum(lsum);
    if (lane == 0) red[4 + w] = ws;
    __syncthreads();
    float inv = 1.0f / (red[4] + red[5] + red[6] + red[7]);
    int d = t & 63, gq = t >> 6;
    float part = 0.0f;
    for (int m = gq * 96; m < (gq + 1) * 96; ++m)
        part += sc[m] * qkv[((size_t)(b * LSEQ + m)) * 768 + 512 + nh * 64 + d];
    op[gq][d] = part;
    __syncthreads();
    if (t < 64) {
        float ov = (op[0][t] + op[1][t] + op[2][t] + op[3][t]) * inv;
        o[((size_t)(b * LSEQ + l)) * HD + nh * 64 + t] = ov;
    }
}

// h += o @ out_w + out_b ; 8 rows per block
__global__ void k_outproj(const float* __restrict__ o, const float* __restrict__ w,
                          const float* __restrict__ bias, float* __restrict__ h) {
    __shared__ float os[8][HD];
    int r0 = blockIdx.x * 8;
    int t = threadIdx.x;
#pragma unroll
    for (int r = 0; r < 8; ++r) os[r][t] = o[(r0 + r) * HD + t];
    __syncthreads();
    float acc[8] = {};
    for (int a = 0; a < HD; ++a) {
        float wv = w[a * HD + t];
#pragma unroll
        for (int r = 0; r < 8; ++r) acc[r] += os[r][a] * wv;
    }
    float bv = bias[t];
#pragma unroll
    for (int r = 0; r < 8; ++r) h[(r0 + r) * HD + t] += acc[r] + bv;
}

// mid = gelu(LN(h) @ ff_w1 + b1) ; 8 rows per block
__global__ void k_ff1(const float* __restrict__ h, const float* __restrict__ g,
                      const float* __restrict__ bb, const float* __restrict__ w,
                      const float* __restrict__ b1, float* __restrict__ mid) {
    __shared__ float hs[8][HD];
    __shared__ float red[8];
    int r0 = blockIdx.x * 8;
    int t = threadIdx.x;
    int wv_ = t >> 6, lane = t & 63;
#pragma unroll
    for (int r = 0; r < 8; ++r) hs[r][t] = h[(r0 + r) * HD + t];
    __syncthreads();
    float gt = g[t], bt = bb[t];
    for (int r = 0; r < 8; ++r) {
        float v = hs[r][t];
        float s = wsum(v);
        if (lane == 0) red[wv_] = s;
        __syncthreads();
        float mean = (red[0] + red[1] + red[2] + red[3]) * (1.0f / HD);
        float d = v - mean;
        float q = wsum(d * d);
        if (lane == 0) red[4 + wv_] = q;
        __syncthreads();
        float var = (red[4] + red[5] + red[6] + red[7]) * (1.0f / HD);
        hs[r][t] = d * rsqrtf(var + 1e-5f) * gt + bt;
    }
    __syncthreads();
#pragma unroll
    for (int c = 0; c < 4; ++c) {
        int j = c * HD + t;
        float acc[8] = {};
        for (int a = 0; a < HD; ++a) {
            float wv = w[a * 1024 + j];
#pragma unroll
            for (int r = 0; r < 8; ++r) acc[r] += hs[r][a] * wv;
        }
        float bv = b1[j];
#pragma unroll
        for (int r = 0; r < 8; ++r) mid[(r0 + r) * 1024 + j] = gelu_erf(acc[r] + bv);
    }
}

// h += mid @ ff_w2 + b2 ; 8 rows per block
__global__ void k_ff2(const float* __restrict__ mid, const float* __restrict__ w,
                      const float* __restrict__ b2, float* __restrict__ h) {
    __shared__ float ms[8 * 1024];
    int r0 = blockIdx.x * 8;
    int t = threadIdx.x;
    for (int n = t; n < 8192; n += 256) ms[n] = mid[r0 * 1024 + n];
    __syncthreads();
    float acc[8] = {};
    for (int a = 0; a < 1024; ++a) {
        float wv = w[a * HD + t];
#pragma unroll
        for (int r = 0; r < 8; ++r) acc[r] += ms[r * 1024 + a] * wv;
    }
    float bv = b2[t];
#pragma unroll
    for (int r = 0; r < 8; ++r) h[(r0 + r) * HD + t] += acc[r] + bv;
}

// pair[b,l,m,:] += gelu(LN(oi[b,l]+oj[b,m]+ob) @ w1 + b1) @ w2 + b2
// weight columns live in VGPRs; activation broadcast via readlane (no LDS in loop)
__global__ void __launch_bounds__(256, 2) k_pair_upd(
    const float* __restrict__ oi, const float* __restrict__ oj,
    const float* __restrict__ ob, const float* __restrict__ g,
    const float* __restrict__ bb, const float* __restrict__ w1,
    const float* __restrict__ b1, const float* __restrict__ w2,
    const float* __restrict__ b2, float* __restrict__ pair) {
    __shared__ float ois[PDIM];
    int row = blockIdx.x;            // b*L + l
    int b = row / LSEQ;
    int t = threadIdx.x, wv = t >> 6, lane = t & 63;
    if (t < PDIM) ois[t] = oi[row * PDIM + t];
    float wc1[64], wc2[64];
#pragma unroll
    for (int dd = 0; dd < 64; ++dd) {
        wc1[dd] = w1[dd * 64 + lane];
        wc2[dd] = w2[dd * 64 + lane];
    }
    float gd = g[lane], bd = bb[lane], obv = ob[lane], b1v = b1[lane], b2v = b2[lane];
    const float* ojb = oj + (size_t)b * LSEQ * PDIM;
    float* pr = pair + (size_t)row * LSEQ * PDIM;
    __syncthreads();
    for (int m = wv; m < LSEQ; m += 4) {
        float v = ois[lane] + ojb[m * PDIM + lane] + obv;
        float mean = wsum(v) * (1.0f / PDIM);
        float d = v - mean;
        float var = wsum(d * d) * (1.0f / PDIM);
        float tn = d * rsqrtf(var + 1e-5f) * gd + bd;
        float acc = b1v;
#pragma unroll
        for (int dd = 0; dd < 64; ++dd) acc += bcast(tn, dd) * wc1[dd];
        float uu = gelu_erf(acc);
        float acc2 = b2v;
#pragma unroll
        for (int dd = 0; dd < 64; ++dd) acc2 += bcast(uu, dd) * wc2[dd];
        pr[m * PDIM + lane] += acc2;
    }
}

// logits (unsymmetrized) = gelu(LN(pair) @ dh_w1 + b1) @ dh_w2 + b2
__global__ void __launch_bounds__(256, 2) k_dist(
    const float* __restrict__ pair, const float* __restrict__ g,
    const float* __restrict__ bb, const float* __restrict__ w1,
    const float* __restrict__ b1, const float* __restrict__ w2,
    const float* __restrict__ b2, float* __restrict__ out) {
    int row = blockIdx.x;            // b*L + l
    int t = threadIdx.x, wv = t >> 6, lane = t & 63;
    float wc1[64], wc2[64];
#pragma unroll
    for (int dd = 0; dd < 64; ++dd) {
        wc1[dd] = w1[dd * 64 + lane];
        wc2[dd] = w2[dd * 65 + lane];
    }
    float w2c64 = w2[lane * 65 + 64];
    float gd = g[lane], bd = bb[lane], b1v = b1[lane], b2v = b2[lane];
    float b2last = b2[64];
    const float* pr = pair + (size_t)row * LSEQ * PDIM;
    float* orow = out + (size_t)row * LSEQ * NBINS;
    for (int m = wv; m < LSEQ; m += 4) {
        float v = pr[m * PDIM + lane];
        float mean = wsum(v) * (1.0f / PDIM);
        float d = v - mean;
        float var = wsum(d * d) * (1.0f / PDIM);
        float tn = d * rsqrtf(var + 1e-5f) * gd + bd;
        float acc = b1v;
#pragma unroll
        for (int dd = 0; dd < 64; ++dd) acc += bcast(tn, dd) * wc1[dd];
        float uu = gelu_erf(acc);
        float acc2 = b2v;
#pragma unroll
        for (int dd = 0; dd < 64; ++dd) acc2 += bcast(uu, dd) * wc2[dd];
        float c64 = wsum(uu * w2c64);
        orow[m * NBINS + lane] = acc2;
        if (lane == 0) orow[m * NBINS + 64] = c64 + b2last;
    }
}

// out = (out + out^T(1,2)) / 2, in place; block (b,l) owns pairs (l,m) m>=l
__global__ void k_sym(float* __restrict__ out) {
    int row = blockIdx.x;            // b*L + l
    int b = row / LSEQ, l = row % LSEQ;
    int t = threadIdx.x;
    float* obp = out + (size_t)b * LSEQ * LSEQ * NBINS;
    int tot = (LSEQ - l) * NBINS;
    for (int n = t; n < tot; n += 256) {
        int m = l + n / NBINS;
        int k = n % NBINS;
        size_t i1 = ((size_t)l * LSEQ + m) * NBINS + k;
        size_t i2 = ((size_t)m * LSEQ + l) * NBINS + k;
        float a = obp[i1], c = obp[i2];
        float vv = 0.5f * (a + c);
        obp[i1] = vv;
        obp[i2] = vv;
    }
}

extern "C" void kernel_launch(void* const* d_in, const int* in_sizes, int n_in,
                              void* d_out, int out_size, void* d_ws, size_t ws_size,
                              hipStream_t stream) {
    const float* x        = (const float*)d_in[0];
    const float* rp_w     = (const float*)d_in[1];
    const float* rp_b     = (const float*)d_in[2];
    const float* pos      = (const float*)d_in[3];
    const float* pii_w    = (const float*)d_in[4];
    const float* pii_b    = (const float*)d_in[5];
    const float* pij_w    = (const float*)d_in[6];
    const float* pij_b    = (const float*)d_in[7];
    const float* rel_emb  = (const float*)d_in[8];
    const float* ln_seq_g = (const float*)d_in[9];
    const float* ln_seq_b = (const float*)d_in[10];
    const float* ln_pair_g= (const float*)d_in[11];
    const float* ln_pair_b= (const float*)d_in[12];
    const float* pb_w     = (const float*)d_in[13];
    const float* in_w     = (const float*)d_in[14];
    const float* in_b     = (const float*)d_in[15];
    const float* out_w    = (const float*)d_in[16];
    const float* out_b    = (const float*)d_in[17];
    const float* ff_ln_g  = (const float*)d_in[18];
    const float* ff_ln_b  = (const float*)d_in[19];
    const float* ff_w1    = (const float*)d_in[20];
    const float* ff_b1    = (const float*)d_in[21];
    const float* ff_w2    = (const float*)d_in[22];
    const float* ff_b2    = (const float*)d_in[23];
    const float* pu_ln_g  = (const float*)d_in[24];
    const float* pu_ln_b  = (const float*)d_in[25];
    const float* pu_w1    = (const float*)d_in[26];
    const float* pu_b1    = (const float*)d_in[27];
    const float* pu_w2    = (const float*)d_in[28];
    const float* pu_b2    = (const float*)d_in[29];
    const float* outer_w  = (const float*)d_in[30];
    const float* outer_b  = (const float*)d_in[31];
    const float* dh_ln_g  = (const float*)d_in[32];
    const float* dh_ln_b  = (const float*)d_in[33];
    const float* dh_w1    = (const float*)d_in[34];
    const float* dh_b1    = (const float*)d_in[35];
    const float* dh_w2    = (const float*)d_in[36];
    const float* dh_b2    = (const float*)d_in[37];
    float* outp = (float*)d_out;

    float* W = (float*)d_ws;
    float* h    = W;  W += BATCH * LSEQ * HD;
    float* sn   = W;  W += BATCH * LSEQ * HD;
    float* qkv  = W;  W += BATCH * LSEQ * 3 * HD;
    float* ob   = W;  W += BATCH * LSEQ * HD;
    float* mid  = W;  W += BATCH * LSEQ * 4 * HD;
    float* mask = W;  W += LSEQ * LSEQ;
    float* poi  = W;  W += BATCH * LSEQ * PDIM;
    float* poj  = W;  W += BATCH * LSEQ * PDIM;
    float* pair = W;  W += (size_t)BATCH * LSEQ * LSEQ * PDIM;

    const int rows = BATCH * LSEQ;   // 768

    k_h_init<<<rows, 256, 0, stream>>>(x, rp_w, rp_b, pos, h);
    k_proj2<<<rows, 128, 0, stream>>>(h, pii_w, pij_w, pii_b, pij_b, poi, poj);
    k_pair_init<<<rows, 256, 0, stream>>>(poi, poj, rel_emb, pair);

    for (int i = 0; i < 4; ++i) {
        k_ln_seq<<<rows, 256, 0, stream>>>(h, ln_seq_g + i * HD, ln_seq_b + i * HD, sn);
        k_mask<<<LSEQ * LSEQ / 4, 256, 0, stream>>>(pair, ln_pair_g + i * PDIM,
                                                    ln_pair_b + i * PDIM,
                                                    pb_w + i * PDIM * NHEAD, mask);
        k_qkv<<<rows / 8, 256, 0, stream>>>(sn, in_w + i * HD * 3 * HD, in_b + i * 3 * HD, qkv);
        k_attn<<<BATCH * NHEAD * LSEQ, 256, 0, stream>>>(qkv, mask, ob);
        k_outproj<<<rows / 8, 256, 0, stream>>>(ob, out_w + i * HD * HD, out_b + i * HD, h);
        k_ff1<<<rows / 8, 256, 0, stream>>>(h, ff_ln_g + i * HD, ff_ln_b + i * HD,
                                            ff_w1 + i * HD * 4 * HD, ff_b1 + i * 4 * HD, mid);
        k_ff2<<<rows / 8, 256, 0, stream>>>(mid, ff_w2 + i * 4 * HD * HD, ff_b2 + i * HD, h);
        k_proj2<<<rows, 128, 0, stream>>>(h, outer_w + i * 2 * HD * PDIM,
                                          outer_w + i * 2 * HD * PDIM + HD * PDIM,
                                          nullptr, nullptr, poi, poj);
        k_pair_upd<<<rows, 256, 0, stream>>>(poi, poj, outer_b + i * PDIM,
                                             pu_ln_g + i * PDIM, pu_ln_b + i * PDIM,
                                             pu_w1 + i * PDIM * PDIM, pu_b1 + i * PDIM,
                                             pu_w2 + i * PDIM * PDIM, pu_b2 + i * PDIM, pair);
    }

    k_dist<<<rows, 256, 0, stream>>>(pair, dh_ln_g, dh_ln_b, dh_w1, dh_b1, dh_w2, dh_b2, outp);
    k_sym<<<rows, 256, 0, stream>>>(outp);
}